// Round 9
// baseline (139.832 us; speedup 1.0000x reference)
//
#include <hip/hip_runtime.h>
#include <stdint.h>

#define B 8
#define N 460800
#define NV4 115200          // N/4 float4 scores per image
#define PRE 2000
#define POST 1000
#define CAP 4096
#define NBIN 4096
#define RANKP 2048
#define NWORD 32
#define NMS_T 0.7f
#define XCLIP 4.135166556742356

#define SCAN_BLOCKS 45      // 45*256*10 = 115200
#define SCAN_ITER 10
#define SCAN_STRIDE (SCAN_BLOCKS * 256)

typedef unsigned long long u64;

__device__ __forceinline__ uint32_t fkey(float f) {
    uint32_t u = __float_as_uint(f);
    return (u & 0x80000000u) ? ~u : (u | 0x80000000u);
}

__device__ __forceinline__ u64 readlane_u64(u64 v, int lane) {
    uint32_t lo = __builtin_amdgcn_readlane((uint32_t)v, lane);
    uint32_t hi = __builtin_amdgcn_readlane((uint32_t)(v >> 32), lane);
    return ((u64)hi << 32) | lo;
}

// async global->LDS DMA, 16B per lane: dest = lds_base (uniform) + lane*16,
// src = per-lane global address. Linear layout both sides (m104/m108 constraint).
__device__ __forceinline__ void gload_lds16(const void* g, void* l) {
    __builtin_amdgcn_global_load_lds(
        (const __attribute__((address_space(1))) void*)g,
        (__attribute__((address_space(3))) void*)l, 16, 0, 0);
}

// ---------------- Stage 1: per-image histogram of score keys (top 12 bits) ----------------
__global__ __launch_bounds__(256) void k_hist(const float4* __restrict__ obj4,
                                              uint32_t* __restrict__ hist) {
    __shared__ uint32_t lh[2][NBIN];   // 32 KiB, 2-way replicated to cut contention
    int b = blockIdx.y;
    for (int i = threadIdx.x; i < NBIN; i += 256) { lh[0][i] = 0; lh[1][i] = 0; }
    __syncthreads();
    const float4* s = obj4 + (size_t)b * NV4;
    int t0 = blockIdx.x * 256 + threadIdx.x;
    uint32_t* h = lh[threadIdx.x & 1];
    float4 v[SCAN_ITER];
#pragma unroll
    for (int k = 0; k < SCAN_ITER; ++k) v[k] = s[t0 + k * SCAN_STRIDE];
#pragma unroll
    for (int k = 0; k < SCAN_ITER; ++k) {
        atomicAdd(&h[fkey(v[k].x) >> 20], 1u);
        atomicAdd(&h[fkey(v[k].y) >> 20], 1u);
        atomicAdd(&h[fkey(v[k].z) >> 20], 1u);
        atomicAdd(&h[fkey(v[k].w) >> 20], 1u);
    }
    __syncthreads();
    uint32_t* gh = hist + (size_t)b * NBIN;
    for (int i = threadIdx.x; i < NBIN; i += 256) {
        uint32_t s2 = lh[0][i] + lh[1][i];
        if (s2) atomicAdd(&gh[i], s2);
    }
}

// ---------------- Stage 2: find cutoff bin (2000th largest falls in it) ----------------
__global__ void k_cut(const uint32_t* __restrict__ hist, uint32_t* __restrict__ cut) {
    int b = blockIdx.x;
    int lane = threadIdx.x;  // 0..63, one wave
    const uint32_t* h = hist + (size_t)b * NBIN;
    uint32_t gs = 0;
    for (int t = 0; t < 64; ++t) gs += h[lane * 64 + t];
    uint32_t suf = gs;
    for (int d = 1; d < 64; d <<= 1) {
        uint32_t v = __shfl_down(suf, d);
        if (lane + d < 64) suf += v;
    }
    unsigned long long m = __ballot(suf >= PRE);
    int G = 63 - __clzll(m);
    uint32_t A = 0;
    if (G < 63) A = __shfl(suf, G + 1);
    uint32_t hv = h[G * 64 + lane];
    uint32_t suf2 = hv;
    for (int d = 1; d < 64; d <<= 1) {
        uint32_t v = __shfl_down(suf2, d);
        if (lane + d < 64) suf2 += v;
    }
    unsigned long long m2 = __ballot(A + suf2 >= PRE);
    int t2 = 63 - __clzll(m2);
    if (lane == 0) cut[b] = (uint32_t)(G * 64 + t2);
}

// ---------------- Stage 3: compact candidates (bin >= cut), 1 global atomic / block ------
#define LBUF 2048
__global__ __launch_bounds__(256) void k_compact(const float4* __restrict__ obj4,
                                                 const uint32_t* __restrict__ cut,
                                                 uint32_t* __restrict__ cnt,
                                                 u64* __restrict__ cand) {
    __shared__ u64 buf[LBUF];          // 16 KiB
    __shared__ uint32_t lcnt, base;
    int b = blockIdx.y;
    if (threadIdx.x == 0) lcnt = 0;
    __syncthreads();
    uint32_t cb = cut[b];
    const float4* s = obj4 + (size_t)b * NV4;
    int t0 = blockIdx.x * 256 + threadIdx.x;
    float4 v[SCAN_ITER];
#pragma unroll
    for (int k = 0; k < SCAN_ITER; ++k) v[k] = s[t0 + k * SCAN_STRIDE];
#pragma unroll
    for (int k = 0; k < SCAN_ITER; ++k) {
        int i4 = (t0 + k * SCAN_STRIDE) * 4;
        float fv[4] = {v[k].x, v[k].y, v[k].z, v[k].w};
#pragma unroll
        for (int c = 0; c < 4; ++c) {
            uint32_t key = fkey(fv[c]);
            if ((key >> 20) >= cb) {
                uint32_t p = atomicAdd(&lcnt, 1u);
                u64 e = ((u64)key << 32) | (uint32_t)(~(uint32_t)(i4 + c));
                if (p < LBUF) buf[p] = e;
                else {   // never expected; correctness fallback
                    uint32_t g = atomicAdd(&cnt[b], 1u);
                    if (g < CAP) cand[(size_t)b * CAP + g] = e;
                }
            }
        }
    }
    __syncthreads();
    uint32_t nb = lcnt < LBUF ? lcnt : LBUF;
    if (threadIdx.x == 0) base = atomicAdd(&cnt[b], nb);
    __syncthreads();
    uint32_t bs = base;
    for (uint32_t t = threadIdx.x; t < nb; t += 256) {
        uint32_t g = bs + t;
        if (g < CAP) cand[(size_t)b * CAP + g] = buf[t];
    }
}

// ---------------- Stage 4: hybrid register/shfl/LDS bitonic sort, desc by (key, ~idx) ----
__device__ __forceinline__ u64 bmax(u64 a, u64 b) { return a > b ? a : b; }
__device__ __forceinline__ u64 bmin(u64 a, u64 b) { return a < b ? a : b; }

__global__ __launch_bounds__(1024) void k_sort(const uint32_t* __restrict__ cnt,
                                               const u64* __restrict__ cand,
                                               uint32_t* __restrict__ topidx) {
    __shared__ u64 sm[CAP];  // 32 KiB
    int b = blockIdx.x;
    uint32_t n = cnt[b]; if (n > CAP) n = CAP;
    const u64* c = cand + (size_t)b * CAP;
    int tid = threadIdx.x;
    int e0 = tid * 4;
    u64 v[4];
#pragma unroll
    for (int i = 0; i < 4; ++i) v[i] = (e0 + i < (int)n) ? c[e0 + i] : 0ull;

    for (unsigned k = 2; k <= CAP; k <<= 1) {
        for (unsigned j = k >> 1; j; j >>= 1) {
            if (j >= 256) {
                __syncthreads();
#pragma unroll
                for (int i = 0; i < 4; ++i) sm[e0 + i] = v[i];
                __syncthreads();
#pragma unroll
                for (int i = 0; i < 4; ++i) {
                    int e = e0 + i;
                    u64 o = sm[e ^ j];
                    bool lower = (e & j) == 0;
                    bool desc  = (e & k) == 0;
                    v[i] = (lower == desc) ? bmax(v[i], o) : bmin(v[i], o);
                }
            } else if (j >= 4) {
                int ld = j >> 2;   // lane xor, 1..32
#pragma unroll
                for (int i = 0; i < 4; ++i) {
                    int e = e0 + i;
                    u64 o = __shfl_xor(v[i], ld);
                    bool lower = (e & j) == 0;
                    bool desc  = (e & k) == 0;
                    v[i] = (lower == desc) ? bmax(v[i], o) : bmin(v[i], o);
                }
            } else {
#pragma unroll
                for (int i = 0; i < 4; ++i) {
                    int e = e0 + i;
                    if ((e & j) == 0) {
                        int i2 = i + (int)j;
                        bool desc = (e & k) == 0;
                        u64 mx = bmax(v[i], v[i2]), mn = bmin(v[i], v[i2]);
                        v[i]  = desc ? mx : mn;
                        v[i2] = desc ? mn : mx;
                    }
                }
            }
        }
    }
#pragma unroll
    for (int i = 0; i < 4; ++i) {
        int r = e0 + i;
        if (r < PRE) topidx[(size_t)b * RANKP + r] = ~(uint32_t)v[i];
    }
}

// ---------------- Stage 5: decode + clip + small-box mask for top-2000 ----------------
__global__ void k_decode(const float4* __restrict__ anchors, const float4* __restrict__ deltas,
                         const uint32_t* __restrict__ topidx, float4* __restrict__ boxes,
                         u64* __restrict__ valid) {
    int b = blockIdx.y;
    int r = blockIdx.x * blockDim.x + threadIdx.x;  // 0..2047
    float4 out = make_float4(0.f, 0.f, 0.f, 0.f);
    bool ok = false;
    if (r < PRE) {
        uint32_t i = topidx[(size_t)b * RANKP + r];
        if (i < N) {
            float4 a = anchors[i];
            float4 d = deltas[(size_t)b * N + i];
            float w = a.z - a.x, h = a.w - a.y;
            float cx = a.x + 0.5f * w, cy = a.y + 0.5f * h;
            float dw = fminf(d.z, (float)XCLIP);
            float dh = fminf(d.w, (float)XCLIP);
            float pcx = d.x * w + cx, pcy = d.y * h + cy;
            float pw = expf(dw) * w, ph = expf(dh) * h;
            float x1 = pcx - 0.5f * pw, y1 = pcy - 0.5f * ph;
            float x2 = pcx + 0.5f * pw, y2 = pcy + 0.5f * ph;
            x1 = fminf(fmaxf(x1, 0.f), 1024.f);
            y1 = fminf(fmaxf(y1, 0.f), 1024.f);
            x2 = fminf(fmaxf(x2, 0.f), 1024.f);
            y2 = fminf(fmaxf(y2, 0.f), 1024.f);
            out = make_float4(x1, y1, x2, y2);
            ok = !((x2 - x1 < 1e-3f) || (y2 - y1 < 1e-3f));
        }
    }
    boxes[(size_t)b * RANKP + r] = out;
    u64 bal = __ballot(ok);
    if ((threadIdx.x & 63) == 0) valid[(size_t)b * NWORD + (r >> 6)] = bal;
}

// ---------------- Stage 6a: pairwise suppression bitmask (triangular grid) ----------------
// Diagonal blocks (ti==tj) additionally write their word to the compact diagd array
// (diagd[b][chunk][row]) so k_nms can coalesce-load all diagonals once.
#define NTRI (NWORD * (NWORD + 1) / 2)   // 528
__global__ void k_mask(const float4* __restrict__ boxes, u64* __restrict__ sup,
                       u64* __restrict__ diagd) {
    int b = blockIdx.y;
    int L = blockIdx.x;
    int ti = 0, rem = L;
    while (rem >= NWORD - ti) { rem -= NWORD - ti; ++ti; }
    int tj = ti + rem;
    __shared__ float4 jb[64];
    __shared__ float ja[64];
    int t = threadIdx.x;  // 64 threads
    const float4* bx = boxes + (size_t)b * RANKP;
    float4 v = bx[tj * 64 + t];
    jb[t] = v;
    ja[t] = (v.z - v.x) * (v.w - v.y);
    int i = ti * 64 + t;
    float4 bi = bx[i];
    float ai = (bi.z - bi.x) * (bi.w - bi.y);
    __syncthreads();
    u64 word = 0;
    for (int jj = 0; jj < 64; ++jj) {
        int j = tj * 64 + jj;
        float4 bj = jb[jj];
        float xx1 = fmaxf(bi.x, bj.x), yy1 = fmaxf(bi.y, bj.y);
        float xx2 = fminf(bi.z, bj.z), yy2 = fminf(bi.w, bj.w);
        float iw = fmaxf(xx2 - xx1, 0.f), ih = fmaxf(yy2 - yy1, 0.f);
        float inter = iw * ih;
        float iou = inter / (ai + ja[jj] - inter);
        if (j > i && iou > NMS_T) word |= 1ull << jj;
    }
    sup[((size_t)b * RANKP + i) * NWORD + tj] = word;
    if (ti == tj) diagd[((size_t)b * NWORD + ti) * 64 + t] = word;
}

// ---------------- Stage 6b+7: chunked greedy NMS, 3-deep DMA pipeline ----------------
// step1 = serial scalar recurrence on the diagonal tile (diagd preloaded to LDS once,
// batched readlane -> pure SALU chain); step2 = parallel OR of kept rows into remv,
// rows read inline from a 3-deep LDS ring filled by global_load_lds DMA with COUNTED
// vmcnt(32) waits (exactly 16 VMEM ops per chunk; batch c+1 completes ~2 chunks after
// issue -> remote-L2 latency covered). sup lower-triangle words (w < row's chunk) are
// NEVER written (0xAA poison) — the `lane >= c` guard keeps them out of remv.
// Early exit once kept count >= POST: all output positions < POST are then final.
__global__ __launch_bounds__(64, 1) void k_nms(const u64* __restrict__ valid,
                                               const u64* __restrict__ sup,
                                               const u64* __restrict__ diagd,
                                               const float4* __restrict__ boxes,
                                               float4* __restrict__ out) {
    __shared__ u64 Dg[NWORD * 64];      // 16 KiB: all 32 diagonal tiles
    __shared__ u64 Bf[3][64 * NWORD];   // 3 x 16 KiB chunk ring buffer
    int b = blockIdx.x;
    int lane = threadIdx.x;             // 64
    int w = lane & 31, hh = lane >> 5;
    const u64* S = sup + (size_t)b * RANKP * NWORD;
    u64 remv = (lane < 32) ? ~valid[(size_t)b * NWORD + lane] : 0ull;
    // force the valid load (and its wait) to materialize before the DMA stream starts
    asm volatile("" :: "v"((uint32_t)remv), "v"((uint32_t)(remv >> 32)));
    // preload all diagonals (16 ops) + chunk batches 0..2 (48 ops)
    {
        const char* gd = (const char*)(diagd + (size_t)b * (NWORD * 64));
        char* ld = (char*)&Dg[0];
#pragma unroll
        for (int i = 0; i < 16; ++i)
            gload_lds16(gd + i * 1024 + lane * 16, ld + i * 1024);
#pragma unroll
        for (int t = 0; t < 3; ++t) {
            const char* gn = (const char*)(S + (size_t)t * 64 * NWORD);
            char* lb = (char*)&Bf[t][0];
#pragma unroll
            for (int i = 0; i < 16; ++i)
                gload_lds16(gn + i * 1024 + lane * 16, lb + i * 1024);
        }
    }
    asm volatile("s_waitcnt vmcnt(32)" ::: "memory");   // Dg + batch0 complete
    int kept_cnt = 0;
    for (int c = 0; c < NWORD; ++c) {
        int buf = c % 3;
        // ---- step1: serial scalar recurrence on diagonal tile (from Dg) ----
        u64 dcur = Dg[(c << 6) + lane];
        u64 scur = readlane_u64(remv, c);
#pragma unroll
        for (int g = 0; g < 4; ++g) {
            u64 d[16];
#pragma unroll
            for (int i = 0; i < 16; ++i) d[i] = readlane_u64(dcur, g * 16 + i);
#pragma unroll
            for (int i = 0; i < 16; ++i) {
                int row = g * 16 + i;
                if (!((scur >> row) & 1ull)) scur |= d[i];   // s_lshr/s_and/s_cselect/s_or
            }
        }
        u64 kept = ~scur;
        // ---- step2: OR kept rows into remv, rows read inline from LDS ring ----
        uint32_t kk = hh ? (uint32_t)(kept >> 32) : (uint32_t)kept;
        u64 acc = 0;
#pragma unroll
        for (int r = 0; r < 32; ++r) {
            u64 m = (u64)(int64_t)((int32_t)(kk << (31 - r)) >> 31);  // replicate bit r
            acc |= Bf[buf][(hh * 32 + r) * NWORD + w] & m;
        }
        u64 acco = __shfl(acc, lane + 32);   // partner half's accumulation
        if (lane < 32 && lane >= c) remv |= (acc | acco);
        kept_cnt += (int)__popcll(kept);
        // ---- issue batch c+3 into the buffer just consumed (reads already issued) ----
        __builtin_amdgcn_sched_barrier(0);
        {
            int cn = (c + 3) & (NWORD - 1);   // wrapped issues are never read; keeps counts fixed
            const char* gn = (const char*)(S + (size_t)cn * 64 * NWORD);
            char* lb = (char*)&Bf[buf][0];
#pragma unroll
            for (int i = 0; i < 16; ++i)
                gload_lds16(gn + i * 1024 + lane * 16, lb + i * 1024);
        }
        asm volatile("s_waitcnt vmcnt(32)" ::: "memory");  // batch c+1 complete
        if (kept_cnt >= POST) break;
    }
    // ---- epilogue: stable partition (kept first) -> top-1000 gather ----
    int tot = 0;
    for (int ww = 0; ww < NWORD; ++ww)
        tot += (int)__popcll(~readlane_u64(remv, ww));
    u64 below = (1ull << lane) - 1ull;
    int kcum = 0, ucum = 0;
    for (int ww = 0; ww < NWORD; ++ww) {
        u64 kw = ~readlane_u64(remv, ww);
        int pc = (int)__popcll(kw);
        bool kp = (kw >> lane) & 1ull;
        int pos;
        if (kp) pos = kcum + (int)__popcll(kw & below);
        else    pos = tot + ucum + (int)__popcll((~kw) & below);
        if (pos < POST) out[(size_t)b * POST + pos] = boxes[(size_t)b * RANKP + ww * 64 + lane];
        kcum += pc;
        ucum += 64 - pc;
    }
}

extern "C" void kernel_launch(void* const* d_in, const int* in_sizes, int n_in,
                              void* d_out, int out_size, void* d_ws, size_t ws_size,
                              hipStream_t stream) {
    const float* anchors = (const float*)d_in[0];   // [N,4]
    const float* obj     = (const float*)d_in[1];   // [B,N]
    const float* deltas  = (const float*)d_in[2];   // [B,N,4]
    char* ws = (char*)d_ws;

    uint32_t* hist   = (uint32_t*)(ws + 0);        // 131072
    uint32_t* cnt    = (uint32_t*)(ws + 131072);   // 256
    uint32_t* cut    = (uint32_t*)(ws + 131328);   // 256
    u64*      cand   = (u64*)(ws + 131584);        // B*4096*8 = 262144 -> 393728
    uint32_t* topidx = (uint32_t*)(ws + 393728);   // B*2048*4 = 65536  -> 459264
    float4*   boxes  = (float4*)(ws + 459264);     // B*2048*16 = 524288 -> 983552
    u64*      valid  = (u64*)(ws + 983552);        // 2048 -> 985600
    u64*      sup    = (u64*)(ws + 985600);        // B*2048*32*8 = 4194304 -> 5179904
    u64*      diagd  = (u64*)(ws + 5179904);       // B*32*64*8 = 131072 -> 5310976

    hipMemsetAsync(ws, 0, 131328, stream);  // hist + cnt

    dim3 gscan(SCAN_BLOCKS, B);
    k_hist<<<gscan, 256, 0, stream>>>((const float4*)obj, hist);
    k_cut<<<B, 64, 0, stream>>>(hist, cut);
    k_compact<<<gscan, 256, 0, stream>>>((const float4*)obj, cut, cnt, cand);
    k_sort<<<B, 1024, 0, stream>>>(cnt, cand, topidx);
    dim3 gdec(RANKP / 256, B);
    k_decode<<<gdec, 256, 0, stream>>>((const float4*)anchors, (const float4*)deltas,
                                       topidx, boxes, valid);
    dim3 gmask(NTRI, B);
    k_mask<<<gmask, 64, 0, stream>>>(boxes, sup, diagd);
    k_nms<<<B, 64, 0, stream>>>(valid, sup, diagd, boxes, (float4*)d_out);
}

// Round 10
// 137.078 us; speedup vs baseline: 1.0201x; 1.0201x over previous
//
#include <hip/hip_runtime.h>
#include <stdint.h>

#define B 8
#define N 460800
#define NV4 115200          // N/4 float4 scores per image
#define PRE 2000
#define POST 1000
#define CAP 4096
#define NBIN 4096
#define RANKP 2048
#define NWORD 32
#define NMS_T 0.7f
#define XCLIP 4.135166556742356

#define SCAN_BLOCKS 45      // 45*256*10 = 115200
#define SCAN_ITER 10
#define SCAN_STRIDE (SCAN_BLOCKS * 256)

typedef unsigned long long u64;

__device__ __forceinline__ uint32_t fkey(float f) {
    uint32_t u = __float_as_uint(f);
    return (u & 0x80000000u) ? ~u : (u | 0x80000000u);
}

__device__ __forceinline__ u64 readlane_u64(u64 v, int lane) {
    uint32_t lo = __builtin_amdgcn_readlane((uint32_t)v, lane);
    uint32_t hi = __builtin_amdgcn_readlane((uint32_t)(v >> 32), lane);
    return ((u64)hi << 32) | lo;
}

// async global->LDS DMA, 16B per lane: dest = lds_base (uniform) + lane*16,
// src = per-lane global address. Linear layout both sides (m104/m108 constraint).
__device__ __forceinline__ void gload_lds16(const void* g, void* l) {
    __builtin_amdgcn_global_load_lds(
        (const __attribute__((address_space(1))) void*)g,
        (__attribute__((address_space(3))) void*)l, 16, 0, 0);
}

// ---------------- Stage 1: per-image histogram of score keys (top 12 bits) ----------------
__global__ __launch_bounds__(256) void k_hist(const float4* __restrict__ obj4,
                                              uint32_t* __restrict__ hist) {
    __shared__ uint32_t lh[2][NBIN];   // 32 KiB, 2-way replicated to cut contention
    int b = blockIdx.y;
    for (int i = threadIdx.x; i < NBIN; i += 256) { lh[0][i] = 0; lh[1][i] = 0; }
    __syncthreads();
    const float4* s = obj4 + (size_t)b * NV4;
    int t0 = blockIdx.x * 256 + threadIdx.x;
    uint32_t* h = lh[threadIdx.x & 1];
    float4 v[SCAN_ITER];
#pragma unroll
    for (int k = 0; k < SCAN_ITER; ++k) v[k] = s[t0 + k * SCAN_STRIDE];
#pragma unroll
    for (int k = 0; k < SCAN_ITER; ++k) {
        atomicAdd(&h[fkey(v[k].x) >> 20], 1u);
        atomicAdd(&h[fkey(v[k].y) >> 20], 1u);
        atomicAdd(&h[fkey(v[k].z) >> 20], 1u);
        atomicAdd(&h[fkey(v[k].w) >> 20], 1u);
    }
    __syncthreads();
    uint32_t* gh = hist + (size_t)b * NBIN;
    for (int i = threadIdx.x; i < NBIN; i += 256) {
        uint32_t s2 = lh[0][i] + lh[1][i];
        if (s2) atomicAdd(&gh[i], s2);
    }
}

// ---------------- Stage 2+3 fused: wave 0 computes cutoff bin, then compact ------------
#define LBUF 2048
__global__ __launch_bounds__(256) void k_compact(const float4* __restrict__ obj4,
                                                 const uint32_t* __restrict__ hist,
                                                 uint32_t* __restrict__ cnt,
                                                 u64* __restrict__ cand) {
    __shared__ u64 buf[LBUF];          // 16 KiB
    __shared__ uint32_t lcnt, base, cutsh;
    int b = blockIdx.y;
    if (threadIdx.x == 0) lcnt = 0;
    // wave 0: recompute the cutoff bin (deterministic, same in every block)
    if (threadIdx.x < 64) {
        int lane = threadIdx.x;
        const uint32_t* h = hist + (size_t)b * NBIN;
        uint32_t gs = 0;
        for (int t = 0; t < 64; ++t) gs += h[lane * 64 + t];
        uint32_t suf = gs;
        for (int d = 1; d < 64; d <<= 1) {
            uint32_t vv = __shfl_down(suf, d);
            if (lane + d < 64) suf += vv;
        }
        unsigned long long m = __ballot(suf >= PRE);
        int G = 63 - __clzll(m);
        uint32_t A = 0;
        if (G < 63) A = __shfl(suf, G + 1);
        uint32_t hv = h[G * 64 + lane];
        uint32_t suf2 = hv;
        for (int d = 1; d < 64; d <<= 1) {
            uint32_t vv = __shfl_down(suf2, d);
            if (lane + d < 64) suf2 += vv;
        }
        unsigned long long m2 = __ballot(A + suf2 >= PRE);
        int t2 = 63 - __clzll(m2);
        if (lane == 0) cutsh = (uint32_t)(G * 64 + t2);
    }
    __syncthreads();
    uint32_t cb = cutsh;
    const float4* s = obj4 + (size_t)b * NV4;
    int t0 = blockIdx.x * 256 + threadIdx.x;
    float4 v[SCAN_ITER];
#pragma unroll
    for (int k = 0; k < SCAN_ITER; ++k) v[k] = s[t0 + k * SCAN_STRIDE];
#pragma unroll
    for (int k = 0; k < SCAN_ITER; ++k) {
        int i4 = (t0 + k * SCAN_STRIDE) * 4;
        float fv[4] = {v[k].x, v[k].y, v[k].z, v[k].w};
#pragma unroll
        for (int c = 0; c < 4; ++c) {
            uint32_t key = fkey(fv[c]);
            if ((key >> 20) >= cb) {
                uint32_t p = atomicAdd(&lcnt, 1u);
                u64 e = ((u64)key << 32) | (uint32_t)(~(uint32_t)(i4 + c));
                if (p < LBUF) buf[p] = e;
                else {   // never expected; correctness fallback
                    uint32_t g = atomicAdd(&cnt[b], 1u);
                    if (g < CAP) cand[(size_t)b * CAP + g] = e;
                }
            }
        }
    }
    __syncthreads();
    uint32_t nb = lcnt < LBUF ? lcnt : LBUF;
    if (threadIdx.x == 0) base = atomicAdd(&cnt[b], nb);
    __syncthreads();
    uint32_t bs = base;
    for (uint32_t t = threadIdx.x; t < nb; t += 256) {
        uint32_t g = bs + t;
        if (g < CAP) cand[(size_t)b * CAP + g] = buf[t];
    }
}

// ---------------- Stage 4+5 fused: bitonic sort + decode + clip + valid mask -------------
// Hybrid register/shfl/LDS bitonic (desc by (key,~idx)); after the sort each thread
// holds 4 sorted elements in registers -> decode top-2000 in place, write boxes+valid.
// blockIdx.x = image -> XCD-local boxes/valid for k_mask/k_nms.
__device__ __forceinline__ u64 bmax(u64 a, u64 b) { return a > b ? a : b; }
__device__ __forceinline__ u64 bmin(u64 a, u64 b) { return a < b ? a : b; }

__global__ __launch_bounds__(1024) void k_sortdec(const uint32_t* __restrict__ cnt,
                                                  const u64* __restrict__ cand,
                                                  const float4* __restrict__ anchors,
                                                  const float4* __restrict__ deltas,
                                                  float4* __restrict__ boxes,
                                                  u64* __restrict__ valid) {
    __shared__ u64 sm[CAP];  // 32 KiB
    int b = blockIdx.x;
    uint32_t n = cnt[b]; if (n > CAP) n = CAP;
    const u64* c = cand + (size_t)b * CAP;
    int tid = threadIdx.x;
    int e0 = tid * 4;
    u64 v[4];
#pragma unroll
    for (int i = 0; i < 4; ++i) v[i] = (e0 + i < (int)n) ? c[e0 + i] : 0ull;

    for (unsigned k = 2; k <= CAP; k <<= 1) {
        for (unsigned j = k >> 1; j; j >>= 1) {
            if (j >= 256) {
                __syncthreads();
#pragma unroll
                for (int i = 0; i < 4; ++i) sm[e0 + i] = v[i];
                __syncthreads();
#pragma unroll
                for (int i = 0; i < 4; ++i) {
                    int e = e0 + i;
                    u64 o = sm[e ^ j];
                    bool lower = (e & j) == 0;
                    bool desc  = (e & k) == 0;
                    v[i] = (lower == desc) ? bmax(v[i], o) : bmin(v[i], o);
                }
            } else if (j >= 4) {
                int ld = j >> 2;   // lane xor, 1..32
#pragma unroll
                for (int i = 0; i < 4; ++i) {
                    int e = e0 + i;
                    u64 o = __shfl_xor(v[i], ld);
                    bool lower = (e & j) == 0;
                    bool desc  = (e & k) == 0;
                    v[i] = (lower == desc) ? bmax(v[i], o) : bmin(v[i], o);
                }
            } else {
#pragma unroll
                for (int i = 0; i < 4; ++i) {
                    int e = e0 + i;
                    if ((e & j) == 0) {
                        int i2 = i + (int)j;
                        bool desc = (e & k) == 0;
                        u64 mx = bmax(v[i], v[i2]), mn = bmin(v[i], v[i2]);
                        v[i]  = desc ? mx : mn;
                        v[i2] = desc ? mn : mx;
                    }
                }
            }
        }
    }
    // ---- decode + clip + small-box mask, in place ----
    __syncthreads();                       // done with sm as sort scratch
    uint8_t* okb = (uint8_t*)sm;           // reuse LDS for per-row valid bytes
    float4* bx = boxes + (size_t)b * RANKP;
#pragma unroll
    for (int i = 0; i < 4; ++i) {
        int r = e0 + i;
        if (r < RANKP) {
            float4 outb = make_float4(0.f, 0.f, 0.f, 0.f);
            bool ok = false;
            if (r < PRE) {
                uint32_t idx = ~(uint32_t)v[i];
                if (idx < N) {
                    float4 a = anchors[idx];
                    float4 d = deltas[(size_t)b * N + idx];
                    float w = a.z - a.x, h = a.w - a.y;
                    float cx = a.x + 0.5f * w, cy = a.y + 0.5f * h;
                    float dw = fminf(d.z, (float)XCLIP);
                    float dh = fminf(d.w, (float)XCLIP);
                    float pcx = d.x * w + cx, pcy = d.y * h + cy;
                    float pw = expf(dw) * w, ph = expf(dh) * h;
                    float x1 = pcx - 0.5f * pw, y1 = pcy - 0.5f * ph;
                    float x2 = pcx + 0.5f * pw, y2 = pcy + 0.5f * ph;
                    x1 = fminf(fmaxf(x1, 0.f), 1024.f);
                    y1 = fminf(fmaxf(y1, 0.f), 1024.f);
                    x2 = fminf(fmaxf(x2, 0.f), 1024.f);
                    y2 = fminf(fmaxf(y2, 0.f), 1024.f);
                    outb = make_float4(x1, y1, x2, y2);
                    ok = !((x2 - x1 < 1e-3f) || (y2 - y1 < 1e-3f));
                }
            }
            bx[r] = outb;
            okb[r] = ok ? 1 : 0;
        }
    }
    __syncthreads();
    if (tid < NWORD) {
        u64 m = 0;
        for (int j = 0; j < 64; ++j) m |= (u64)(okb[tid * 64 + j] & 1) << j;
        valid[(size_t)b * NWORD + tid] = m;
    }
}

// ---------------- Stage 6a: pairwise suppression bitmask ----------------
// blockIdx.x = image, so ALL of image b's sup/diagd writes land on XCD b's L2
// (round-robin dispatch: linear_id % 8 == b since gridDim.x == 8). k_nms block b
// then reads them XCD-locally. Diagonal blocks also write the compact diagd array.
#define NTRI (NWORD * (NWORD + 1) / 2)   // 528
__global__ void k_mask(const float4* __restrict__ boxes, u64* __restrict__ sup,
                       u64* __restrict__ diagd) {
    int b = blockIdx.x;
    int L = blockIdx.y;
    int ti = 0, rem = L;
    while (rem >= NWORD - ti) { rem -= NWORD - ti; ++ti; }
    int tj = ti + rem;
    __shared__ float4 jb[64];
    __shared__ float ja[64];
    int t = threadIdx.x;  // 64 threads
    const float4* bx = boxes + (size_t)b * RANKP;
    float4 v = bx[tj * 64 + t];
    jb[t] = v;
    ja[t] = (v.z - v.x) * (v.w - v.y);
    int i = ti * 64 + t;
    float4 bi = bx[i];
    float ai = (bi.z - bi.x) * (bi.w - bi.y);
    __syncthreads();
    u64 word = 0;
    for (int jj = 0; jj < 64; ++jj) {
        int j = tj * 64 + jj;
        float4 bj = jb[jj];
        float xx1 = fmaxf(bi.x, bj.x), yy1 = fmaxf(bi.y, bj.y);
        float xx2 = fminf(bi.z, bj.z), yy2 = fminf(bi.w, bj.w);
        float iw = fmaxf(xx2 - xx1, 0.f), ih = fmaxf(yy2 - yy1, 0.f);
        float inter = iw * ih;
        float iou = inter / (ai + ja[jj] - inter);
        if (j > i && iou > NMS_T) word |= 1ull << jj;
    }
    sup[((size_t)b * RANKP + i) * NWORD + tj] = word;
    if (ti == tj) diagd[((size_t)b * NWORD + ti) * 64 + t] = word;
}

// ---------------- Stage 6b+7: chunked greedy NMS, 3-deep DMA ring ----------------
// step1 = serial scalar recurrence on the diagonal tile (diagd preloaded to LDS once,
// batched readlane -> pure SALU chain); step2 = parallel OR of kept rows into remv,
// rows read inline from a 3-deep LDS ring filled by global_load_lds DMA. With the
// XCD-local sup layout the (compiler-forced) vmcnt drains hit local L2 (~200cy).
// sup lower-triangle words (w < row's chunk) are NEVER written (0xAA poison) — the
// `lane >= c` guard keeps them out of remv. Do not remove it.
// Early exit once kept count >= POST: all output positions < POST are then final.
__global__ __launch_bounds__(64, 1) void k_nms(const u64* __restrict__ valid,
                                               const u64* __restrict__ sup,
                                               const u64* __restrict__ diagd,
                                               const float4* __restrict__ boxes,
                                               float4* __restrict__ out) {
    __shared__ u64 Dg[NWORD * 64];      // 16 KiB: all 32 diagonal tiles
    __shared__ u64 Bf[3][64 * NWORD];   // 3 x 16 KiB chunk ring buffer
    int b = blockIdx.x;
    int lane = threadIdx.x;             // 64
    int w = lane & 31, hh = lane >> 5;
    const u64* S = sup + (size_t)b * RANKP * NWORD;
    u64 remv = (lane < 32) ? ~valid[(size_t)b * NWORD + lane] : 0ull;
    asm volatile("" :: "v"((uint32_t)remv), "v"((uint32_t)(remv >> 32)));
    // preload all diagonals (16 ops) + chunk batches 0..2 (48 ops)
    {
        const char* gd = (const char*)(diagd + (size_t)b * (NWORD * 64));
        char* ld = (char*)&Dg[0];
#pragma unroll
        for (int i = 0; i < 16; ++i)
            gload_lds16(gd + i * 1024 + lane * 16, ld + i * 1024);
#pragma unroll
        for (int t = 0; t < 3; ++t) {
            const char* gn = (const char*)(S + (size_t)t * 64 * NWORD);
            char* lb = (char*)&Bf[t][0];
#pragma unroll
            for (int i = 0; i < 16; ++i)
                gload_lds16(gn + i * 1024 + lane * 16, lb + i * 1024);
        }
    }
    asm volatile("s_waitcnt vmcnt(32)" ::: "memory");   // Dg + batch0 complete
    int kept_cnt = 0;
    for (int c = 0; c < NWORD; ++c) {
        int buf = c % 3;
        // ---- step1: serial scalar recurrence on diagonal tile (from Dg) ----
        u64 dcur = Dg[(c << 6) + lane];
        u64 scur = readlane_u64(remv, c);
#pragma unroll
        for (int g = 0; g < 4; ++g) {
            u64 d[16];
#pragma unroll
            for (int i = 0; i < 16; ++i) d[i] = readlane_u64(dcur, g * 16 + i);
#pragma unroll
            for (int i = 0; i < 16; ++i) {
                int row = g * 16 + i;
                if (!((scur >> row) & 1ull)) scur |= d[i];   // s_lshr/s_and/s_cselect/s_or
            }
        }
        u64 kept = ~scur;
        // ---- step2: OR kept rows into remv, rows read inline from LDS ring ----
        uint32_t kk = hh ? (uint32_t)(kept >> 32) : (uint32_t)kept;
        u64 acc = 0;
#pragma unroll
        for (int r = 0; r < 32; ++r) {
            u64 m = (u64)(int64_t)((int32_t)(kk << (31 - r)) >> 31);  // replicate bit r
            acc |= Bf[buf][(hh * 32 + r) * NWORD + w] & m;
        }
        u64 acco = __shfl(acc, lane + 32);   // partner half's accumulation
        if (lane < 32 && lane >= c) remv |= (acc | acco);
        kept_cnt += (int)__popcll(kept);
        // ---- issue batch c+3 into the buffer just consumed ----
        __builtin_amdgcn_sched_barrier(0);
        {
            int cn = (c + 3) & (NWORD - 1);   // wrapped issues never read; counts stay fixed
            const char* gn = (const char*)(S + (size_t)cn * 64 * NWORD);
            char* lb = (char*)&Bf[buf][0];
#pragma unroll
            for (int i = 0; i < 16; ++i)
                gload_lds16(gn + i * 1024 + lane * 16, lb + i * 1024);
        }
        asm volatile("s_waitcnt vmcnt(32)" ::: "memory");  // batch c+1 complete
        if (kept_cnt >= POST) break;
    }
    // ---- epilogue: stable partition (kept first) -> top-1000 gather ----
    int tot = 0;
    for (int ww = 0; ww < NWORD; ++ww)
        tot += (int)__popcll(~readlane_u64(remv, ww));
    u64 below = (1ull << lane) - 1ull;
    int kcum = 0, ucum = 0;
    for (int ww = 0; ww < NWORD; ++ww) {
        u64 kw = ~readlane_u64(remv, ww);
        int pc = (int)__popcll(kw);
        bool kp = (kw >> lane) & 1ull;
        int pos;
        if (kp) pos = kcum + (int)__popcll(kw & below);
        else    pos = tot + ucum + (int)__popcll((~kw) & below);
        if (pos < POST) out[(size_t)b * POST + pos] = boxes[(size_t)b * RANKP + ww * 64 + lane];
        kcum += pc;
        ucum += 64 - pc;
    }
}

extern "C" void kernel_launch(void* const* d_in, const int* in_sizes, int n_in,
                              void* d_out, int out_size, void* d_ws, size_t ws_size,
                              hipStream_t stream) {
    const float* anchors = (const float*)d_in[0];   // [N,4]
    const float* obj     = (const float*)d_in[1];   // [B,N]
    const float* deltas  = (const float*)d_in[2];   // [B,N,4]
    char* ws = (char*)d_ws;

    uint32_t* hist   = (uint32_t*)(ws + 0);        // 131072
    uint32_t* cnt    = (uint32_t*)(ws + 131072);   // 256
    u64*      cand   = (u64*)(ws + 131584);        // B*4096*8 = 262144 -> 393728
    float4*   boxes  = (float4*)(ws + 393728);     // B*2048*16 = 524288 -> 918016
    u64*      valid  = (u64*)(ws + 918016);        // 2048 -> 920064
    u64*      sup    = (u64*)(ws + 920064);        // B*2048*32*8 = 4194304 -> 5114368
    u64*      diagd  = (u64*)(ws + 5114368);       // B*32*64*8 = 131072 -> 5245440

    hipMemsetAsync(ws, 0, 131328, stream);  // hist + cnt

    dim3 gscan(SCAN_BLOCKS, B);
    k_hist<<<gscan, 256, 0, stream>>>((const float4*)obj, hist);
    k_compact<<<gscan, 256, 0, stream>>>((const float4*)obj, hist, cnt, cand);
    k_sortdec<<<B, 1024, 0, stream>>>(cnt, cand, (const float4*)anchors,
                                      (const float4*)deltas, boxes, valid);
    dim3 gmask(B, NTRI);
    k_mask<<<gmask, 64, 0, stream>>>(boxes, sup, diagd);
    k_nms<<<B, 64, 0, stream>>>(valid, sup, diagd, boxes, (float4*)d_out);
}